// Round 1
// baseline (341.339 us; speedup 1.0000x reference)
//
#include <hip/hip_runtime.h>

// WadaIN modulated conv1d — round 5:
//  * prep: coalesced wave-cooperative style matvec (was 512B-stride divergent
//    gathers, suspected ~100us); wmod written PRE-SWIZZLED (bits[5:4]^=bits[8:7]
//    within each 512B block) so conv's linear global_load_lds + swizzled
//    ds_read is bank-conflict-free (rule: swizzle both-sides-or-neither).
//  * conv: 512-thr blocks, OM=128 x TN=256, w_sh double-buffered.
//    Per ch-chunk: convert+ds_write x | barrier A | issue NEXT chunk's
//    global_load_lds(w) + x f32 loads -> regs | MFMA 5 taps | barrier B.
//    All HBM latency hides under the MFMA window; __syncthreads drains land
//    after ~3000cy of compute (T14/T3-minimum pattern, plain barriers only).
// Fallback (small ws): R3 kernel verbatim.

#define B_    16
#define CIN   256
#define COUT  256
#define KW    5
#define SPK   128
#define TT    8192

#define OM    128   // o per block
#define TN    256   // t per block (fast kernel)
#define BI    32    // input channels per K-chunk
#define NCH   (CIN / BI)   // 8

#define XROWS 264                                  // 260 used (TN + 4 halo)
#define WSLAB (KW * OM * 32)                       // 20480 ushorts per (b,ot,ch)
#define WMOD_BYTES ((size_t)B_ * 2 * NCH * WSLAB * 2)  // 10,485,760 B

typedef __attribute__((ext_vector_type(8))) short short8;
typedef __attribute__((ext_vector_type(4))) float f32x4;
typedef unsigned short ushort_t;
typedef unsigned int uint_t;

__device__ __forceinline__ ushort_t f2bf(float f) {
    uint_t u = __float_as_uint(f);
    u += 0x7FFF + ((u >> 16) & 1);   // RNE
    return (ushort_t)(u >> 16);
}

// ---------------------------------------------------------------------------
// prep: grid (32 og, 16 b), 256 thr. Each block: 8 output channels.
__global__ __launch_bounds__(256) void prep_kernel(
    const float* __restrict__ c_trg, const float* __restrict__ style_w,
    const float* __restrict__ style_b, const float* __restrict__ weight,
    ushort_t* __restrict__ wmod)
{
    __shared__ float c_sh[SPK];
    __shared__ float s_sh[CIN];
    __shared__ float w_l[8 * 1280];     // 8 o x (256 i x 5 k), 40960 B
    __shared__ float dm_sh[8];

    const int og  = blockIdx.x;        // 0..31 -> o = og*8 .. og*8+7
    const int b   = blockIdx.y;
    const int tid = threadIdx.x;

    if (tid < SPK) c_sh[tid] = c_trg[b * SPK + tid];
    __syncthreads();

    // s = c_trg @ style_w^T + b  — one wave per output row, coalesced float2,
    // butterfly reduce. (Old version: per-thread 512B-stride gathers.)
    {
        const int wv   = tid >> 6;
        const int lane = tid & 63;
        const float c0 = c_sh[lane * 2];
        const float c1 = c_sh[lane * 2 + 1];
        for (int rnd = 0; rnd < 64; ++rnd) {
            const int i = rnd * 4 + wv;
            const float2 w2 = *(const float2*)&style_w[(size_t)i * SPK + lane * 2];
            float p = w2.x * c0 + w2.y * c1;
            p += __shfl_xor(p, 32);
            p += __shfl_xor(p, 16);
            p += __shfl_xor(p, 8);
            p += __shfl_xor(p, 4);
            p += __shfl_xor(p, 2);
            p += __shfl_xor(p, 1);
            if (lane == 0) s_sh[i] = p + style_b[i];
        }
    }

    // stage 8-o weight slab (contiguous 40960 B), coalesced float4
    {
        const float* wsrc = weight + (size_t)og * 8 * 1280;
        #pragma unroll
        for (int it = 0; it < 10; ++it)
            *(float4*)&w_l[(it * 256 + tid) * 4] = *(const float4*)&wsrc[(it * 256 + tid) * 4];
    }
    __syncthreads();

    // demod: 32 threads per o
    {
        const int oi   = tid >> 5;
        const int part = tid & 31;
        float a = 0.f;
        #pragma unroll 8
        for (int m = 0; m < 40; ++m) {
            int j = part + m * 32;
            float v = w_l[oi * 1280 + j] * s_sh[j / 5];
            a += v * v;
        }
        a += __shfl_xor(a, 16);
        a += __shfl_xor(a, 8);
        a += __shfl_xor(a, 4);
        a += __shfl_xor(a, 2);
        a += __shfl_xor(a, 1);
        if (part == 0) dm_sh[oi] = rsqrtf(a + 1e-8f);
    }
    __syncthreads();

    // write wmod rows: 320 rows of 32 i (64 B each), PRE-SWIZZLED columns:
    // physical 16B-block = g ^ ((o_l>>1)&3)  <=> byte[5:4] ^= byte[8:7].
    for (int r = tid; r < 320; r += 256) {
        const int oi  = r / 40;
        const int rem = r - oi * 40;
        const int ch  = rem / 5;
        const int k   = rem - ch * 5;
        const int o   = og * 8 + oi;
        const int ot  = o >> 7;
        const int o_l = o & 127;
        const int swz = (o_l >> 1) & 3;
        const float dmv = dm_sh[oi];
        ushort_t* dst = wmod + ((((size_t)(b * 2 + ot) * NCH + ch) * KW + k) * OM + o_l) * 32;
        #pragma unroll
        for (int g = 0; g < 4; ++g) {
            union { ushort_t us[8]; uint4 v; } pk;
            #pragma unroll
            for (int ii = 0; ii < 8; ++ii) {
                int i_l = g * 8 + ii;
                int i_g = ch * 32 + i_l;
                pk.us[ii] = f2bf(w_l[oi * 1280 + i_g * 5 + k] * s_sh[i_g] * dmv);
            }
            *(uint4*)&dst[(g ^ swz) * 8] = pk.v;
        }
    }
}

// ---------------------------------------------------------------------------
// fast conv: 512 thr, 128o x 256t per block, w double-buffered + pipelined.
__global__ __launch_bounds__(512, 2) void conv_mfma_ws2_kernel(
    const float* __restrict__ x, const ushort_t* __restrict__ wmod,
    float* __restrict__ out)
{
    __shared__ __align__(16) ushort_t w_sh[2][WSLAB];    // 2 x 40960 B
    __shared__ __align__(16) ushort_t x_sh[XROWS * 32];  // 16896 B

    const int b   = blockIdx.z;
    const int ot  = blockIdx.y;
    const int o0  = ot * OM;
    const int t0  = blockIdx.x * TN;
    const int tid = threadIdx.x;

    const int lane  = tid & 63;
    const int wv    = tid >> 6;      // 0..7
    const int wm    = wv >> 2;       // 0..1  (o half)
    const int wn    = wv & 3;        // 0..3  (t quarter)
    const int col16 = lane & 15;
    const int quad  = lane >> 4;

    const int rl = lane;             // x-stage: row within 64-row round
    const int i4 = wv;               // x-stage: channel-quad = wave id (coalesced)

    f32x4 acc[4][4];
    #pragma unroll
    for (int mt = 0; mt < 4; ++mt)
        #pragma unroll
        for (int nt = 0; nt < 4; ++nt)
            acc[mt][nt] = (f32x4){0.f, 0.f, 0.f, 0.f};

    const float* xb = x + (size_t)b * CIN * TT;
    const ushort_t* wslab = wmod + (size_t)(b * 2 + ot) * NCH * WSLAB;

    float xr[2][20];                 // f32 x staging regs, ping-pong

    auto stage_w = [&](int ch, int buf) {
        const ushort_t* ws = wslab + (size_t)ch * WSLAB;
        #pragma unroll
        for (int s = 0; s < 5; ++s) {
            const int off = s * 4096 + wv * 512;    // ushort units, 16B/lane
            __builtin_amdgcn_global_load_lds(
                (const __attribute__((address_space(1))) uint_t*)(ws + off + lane * 8),
                (__attribute__((address_space(3))) uint_t*)(&w_sh[buf][off]),
                16, 0, 0);
        }
    };

    auto load_x = [&](int ch, float* dst) {
        const float* xp = xb + (size_t)(ch * BI + i4 * 4) * TT;
        #pragma unroll
        for (int rd = 0; rd < 5; ++rd) {
            int r = rd * 64 + rl;
            if (r < 260) {
                int tg = t0 + r - 2;
                tg = (tg < 0) ? -tg : tg;
                tg = (tg > TT - 1) ? (2 * (TT - 1) - tg) : tg;
                dst[rd * 4 + 0] = xp[tg];
                dst[rd * 4 + 1] = xp[TT + tg];
                dst[rd * 4 + 2] = xp[2 * TT + tg];
                dst[rd * 4 + 3] = xp[3 * TT + tg];
            }
        }
    };

    auto put_x = [&](const float* src) {
        #pragma unroll
        for (int rd = 0; rd < 5; ++rd) {
            int r = rd * 64 + rl;
            if (r < 260) {
                union { ushort_t us[4]; uint2 u2; } p;
                p.us[0] = f2bf(src[rd * 4 + 0]);
                p.us[1] = f2bf(src[rd * 4 + 1]);
                p.us[2] = f2bf(src[rd * 4 + 2]);
                p.us[3] = f2bf(src[rd * 4 + 3]);
                int grp = (i4 >> 1) ^ ((r ^ (r >> 2)) & 3);
                *(uint2*)&x_sh[r * 32 + grp * 8 + (i4 & 1) * 4] = p.u2;
            }
        }
    };

    // prologue: issue chunk 0 (drained at barrier A of iter 0 / reg scoreboard)
    stage_w(0, 0);
    load_x(0, xr[0]);

    #pragma unroll
    for (int ch = 0; ch < NCH; ++ch) {
        const int cur = ch & 1;

        // x(ch) regs are final (prev __syncthreads drained vmcnt(0))
        put_x(xr[cur]);
        __syncthreads();                             // A: x_sh(ch) visible; nothing in flight

        if (ch < NCH - 1) {
            stage_w(ch + 1, cur ^ 1);                // async -> other w buffer
            load_x(ch + 1, xr[cur ^ 1]);             // f32 -> regs, in flight across MFMA
        }
        __builtin_amdgcn_sched_barrier(0);           // pin issues above the MFMA block

        #pragma unroll
        for (int kt = 0; kt < KW; ++kt) {
            short8 a[4], bf[4];
            #pragma unroll
            for (int mt = 0; mt < 4; ++mt) {
                const int row  = kt * OM + wm * 64 + mt * 16 + col16;
                const int slot = quad ^ ((row >> 1) & 3);     // matches prep swizzle
                a[mt] = *(const short8*)&w_sh[cur][row * 32 + slot * 8];
            }
            #pragma unroll
            for (int nt = 0; nt < 4; ++nt) {
                const int r   = wn * 64 + nt * 16 + col16 + kt;
                const int grp = quad ^ ((r ^ (r >> 2)) & 3);  // matches put_x swizzle
                bf[nt] = *(const short8*)&x_sh[r * 32 + grp * 8];
            }
            #pragma unroll
            for (int mt = 0; mt < 4; ++mt)
                #pragma unroll
                for (int nt = 0; nt < 4; ++nt)
                    acc[mt][nt] = __builtin_amdgcn_mfma_f32_16x16x32_bf16(
                        a[mt], bf[nt], acc[mt][nt], 0, 0, 0);
        }

        if (ch < NCH - 1)
            __syncthreads();                         // B: drains next-chunk loads (issued
                                                     // one MFMA-window ago -> ~free)
    }

    // epilogue: leaky relu + store (demod pre-folded)
    #pragma unroll
    for (int mt = 0; mt < 4; ++mt) {
        #pragma unroll
        for (int nt = 0; nt < 4; ++nt) {
            const int t_o = t0 + wn * 64 + nt * 16 + col16;
            #pragma unroll
            for (int reg = 0; reg < 4; ++reg) {
                const int o_l = wm * 64 + mt * 16 + quad * 4 + reg;
                float v = acc[mt][nt][reg];
                v = (v > 0.f) ? v : 0.2f * v;
                out[((size_t)(b * COUT + o0 + o_l)) * TT + t_o] = v;
            }
        }
    }
}

// ---------------------------------------------------------------------------
// Fallback: R3 kernel verbatim (no workspace), known-good at ~419 us.
__global__ __launch_bounds__(256, 3) void conv_mfma_fb_kernel(
    const float* __restrict__ x, const float* __restrict__ c_trg,
    const float* __restrict__ style_w, const float* __restrict__ style_b,
    const float* __restrict__ weight, float* __restrict__ out)
{
    __shared__ ushort_t x_sh[136 * 32];
    __shared__ ushort_t w_sh[KW * 128 * 32];
    __shared__ float    c_sh[SPK];
    __shared__ float    s_sh[CIN];
    __shared__ float    dm_acc[128];
    __shared__ float    dmv[128];

    const int b   = blockIdx.z;
    const int o0  = blockIdx.y * 128;
    const int t0  = blockIdx.x * 128;
    const int tid = threadIdx.x;

    const int lane  = tid & 63;
    const int wvv   = tid >> 6;
    const int wm    = wvv >> 1;
    const int wn    = wvv & 1;
    const int col16 = lane & 15;
    const int quad  = lane >> 4;

    if (tid < SPK) c_sh[tid] = c_trg[b * SPK + tid];
    if (tid < 128) dm_acc[tid] = 0.f;
    __syncthreads();
    {
        float acc = style_b[tid];
        const float* wr = style_w + (size_t)tid * SPK;
        #pragma unroll 4
        for (int j = 0; j < SPK; ++j) acc += c_sh[j] * wr[j];
        s_sh[tid] = acc;
    }

    f32x4 acc[4][4];
    #pragma unroll
    for (int mt = 0; mt < 4; ++mt)
        #pragma unroll
        for (int nt = 0; nt < 4; ++nt)
            acc[mt][nt] = (f32x4){0.f, 0.f, 0.f, 0.f};

    const float* xb = x + (size_t)b * CIN * TT;

    for (int ch = 0; ch < NCH; ++ch) {
        const int i0 = ch * BI;
        __syncthreads();
        {
            const int i4 = tid >> 5;
            const int rls = tid & 31;
            const float* xp = xb + (size_t)(i0 + i4 * 4) * TT;
            #pragma unroll
            for (int rr = 0; rr < 136; rr += 32) {
                int r = rr + rls;
                if (r < 136) {
                    int tg = t0 + r - 2;
                    tg = (tg < 0) ? -tg : tg;
                    tg = (tg > TT - 1) ? (2 * (TT - 1) - tg) : tg;
                    float v0 = xp[tg];
                    float v1 = xp[TT + tg];
                    float v2 = xp[2 * TT + tg];
                    float v3 = xp[3 * TT + tg];
                    union { ushort_t us[4]; uint2 u2; } p;
                    p.us[0] = f2bf(v0); p.us[1] = f2bf(v1);
                    p.us[2] = f2bf(v2); p.us[3] = f2bf(v3);
                    int grp = (i4 >> 1) ^ (r & 3);
                    *(uint2*)&x_sh[r * 32 + grp * 8 + (i4 & 1) * 4] = p.u2;
                }
            }
        }
        {
            const int i4 = tid & 7;
            #pragma unroll
            for (int pass = 0; pass < 4; ++pass) {
                const int o_l = (tid >> 3) + pass * 32;
                const float* wp = weight + ((size_t)(o0 + o_l) * CIN + i0 + i4 * 4) * KW;
                float q[20];
                #pragma unroll
                for (int f = 0; f < 5; ++f)
                    *(float4*)&q[f * 4] = *(const float4*)(wp + f * 4);
                float sv0 = s_sh[i0 + i4 * 4 + 0];
                float sv1 = s_sh[i0 + i4 * 4 + 1];
                float sv2 = s_sh[i0 + i4 * 4 + 2];
                float sv3 = s_sh[i0 + i4 * 4 + 3];
                float m0[5], m1[5], m2[5], m3[5];
                float psum = 0.f;
                #pragma unroll
                for (int k = 0; k < 5; ++k) {
                    m0[k] = q[0 * 5 + k] * sv0;  psum += m0[k] * m0[k];
                    m1[k] = q[1 * 5 + k] * sv1;  psum += m1[k] * m1[k];
                    m2[k] = q[2 * 5 + k] * sv2;  psum += m2[k] * m2[k];
                    m3[k] = q[3 * 5 + k] * sv3;  psum += m3[k] * m3[k];
                }
                atomicAdd(&dm_acc[o_l], psum);
                #pragma unroll
                for (int k = 0; k < 5; ++k) {
                    union { ushort_t us[4]; uint2 u2; } p;
                    p.us[0] = f2bf(m0[k]); p.us[1] = f2bf(m1[k]);
                    p.us[2] = f2bf(m2[k]); p.us[3] = f2bf(m3[k]);
                    *(uint2*)&w_sh[(k * 128 + o_l) * 32 + i4 * 4] = p.u2;
                }
            }
        }
        __syncthreads();
        #pragma unroll
        for (int kt = 0; kt < KW; ++kt) {
            short8 a[4], bf[4];
            #pragma unroll
            for (int mt = 0; mt < 4; ++mt)
                a[mt] = *(const short8*)&w_sh[(kt * 128 + wm * 64 + mt * 16 + col16) * 32 + quad * 8];
            #pragma unroll
            for (int nt = 0; nt < 4; ++nt) {
                int r   = wn * 64 + nt * 16 + col16 + kt;
                int grp = quad ^ (r & 3);
                bf[nt] = *(const short8*)&x_sh[r * 32 + grp * 8];
            }
            #pragma unroll
            for (int mt = 0; mt < 4; ++mt)
                #pragma unroll
                for (int nt = 0; nt < 4; ++nt)
                    acc[mt][nt] = __builtin_amdgcn_mfma_f32_16x16x32_bf16(
                        a[mt], bf[nt], acc[mt][nt], 0, 0, 0);
        }
    }

    __syncthreads();
    if (tid < 128) dmv[tid] = rsqrtf(dm_acc[tid] + 1e-8f);
    __syncthreads();

    #pragma unroll
    for (int mt = 0; mt < 4; ++mt) {
        #pragma unroll
        for (int nt = 0; nt < 4; ++nt) {
            const int t_o = t0 + wn * 64 + nt * 16 + col16;
            #pragma unroll
            for (int reg = 0; reg < 4; ++reg) {
                const int o_l = wm * 64 + mt * 16 + quad * 4 + reg;
                float v = acc[mt][nt][reg] * dmv[o_l];
                v = (v > 0.f) ? v : 0.2f * v;
                out[((size_t)(b * COUT + o0 + o_l)) * TT + t_o] = v;
            }
        }
    }
}

// ---------------------------------------------------------------------------
extern "C" void kernel_launch(void* const* d_in, const int* in_sizes, int n_in,
                              void* d_out, int out_size, void* d_ws, size_t ws_size,
                              hipStream_t stream)
{
    const float* x       = (const float*)d_in[0];
    const float* c_trg   = (const float*)d_in[1];
    const float* style_w = (const float*)d_in[2];
    const float* style_b = (const float*)d_in[3];
    const float* weight  = (const float*)d_in[4];
    float* out = (float*)d_out;

    if (ws_size >= WMOD_BYTES) {
        // fast path: precompute modulated (pre-swizzled) bf16 weights into d_ws
        ushort_t* wmod = (ushort_t*)d_ws;
        prep_kernel<<<dim3(32, 16), dim3(256), 0, stream>>>(
            c_trg, style_w, style_b, weight, wmod);
        conv_mfma_ws2_kernel<<<dim3(TT / TN, COUT / OM, B_), dim3(512), 0, stream>>>(
            x, wmod, out);
    } else {
        conv_mfma_fb_kernel<<<dim3(TT / 128, COUT / 128, B_), dim3(256), 0, stream>>>(
            x, c_trg, style_w, style_b, weight, out);
    }

    hipMemcpyAsync(out + (size_t)B_ * COUT * TT, c_trg,
                   (size_t)B_ * SPK * sizeof(float),
                   hipMemcpyDeviceToDevice, stream);
}

// Round 2
// 307.331 us; speedup vs baseline: 1.1107x; 1.1107x over previous
//
#include <hip/hip_runtime.h>

// WadaIN modulated conv1d — round 6:
//  * conv: same 2-barrier pipelined schedule as R5, but the x register
//    staging is now SPILL-FREE: lambdas + runtime-indexed xr[2][20] (which
//    went to scratch, VGPR_Count=104 -> pipeline never engaged) replaced by
//    macro-expanded chunk bodies with named xr0/xr1 and literal w_sh buffer
//    indices. All indices compile-time -> full VGPR promotion (rule #20).
//  * prep: matvec reverted to the R4-proven strided version (R5's
//    shfl-reduce variant correlated with the +27us total regression);
//    wmod still written PRE-SWIZZLED (g ^ (o_l>>1)&3) to match conv's
//    bank-conflict-free ds_read pattern.
// Fallback (small ws): R3 kernel verbatim.

#define B_    16
#define CIN   256
#define COUT  256
#define KW    5
#define SPK   128
#define TT    8192

#define OM    128   // o per block
#define TN    256   // t per block (fast kernel)
#define BI    32    // input channels per K-chunk
#define NCH   (CIN / BI)   // 8

#define XROWS 264                                  // 260 used (TN + 4 halo)
#define WSLAB (KW * OM * 32)                       // 20480 ushorts per (b,ot,ch)
#define WMOD_BYTES ((size_t)B_ * 2 * NCH * WSLAB * 2)  // 10,485,760 B

typedef __attribute__((ext_vector_type(8))) short short8;
typedef __attribute__((ext_vector_type(4))) float f32x4;
typedef unsigned short ushort_t;
typedef unsigned int uint_t;

__device__ __forceinline__ ushort_t f2bf(float f) {
    uint_t u = __float_as_uint(f);
    u += 0x7FFF + ((u >> 16) & 1);   // RNE
    return (ushort_t)(u >> 16);
}

// ---------------------------------------------------------------------------
// prep: grid (32 og, 16 b), 256 thr. Each block: 8 output channels.
__global__ __launch_bounds__(256) void prep_kernel(
    const float* __restrict__ c_trg, const float* __restrict__ style_w,
    const float* __restrict__ style_b, const float* __restrict__ weight,
    ushort_t* __restrict__ wmod)
{
    __shared__ float c_sh[SPK];
    __shared__ float s_sh[CIN];
    __shared__ float w_l[8 * 1280];     // 8 o x (256 i x 5 k), 40960 B
    __shared__ float dm_sh[8];

    const int og  = blockIdx.x;        // 0..31 -> o = og*8 .. og*8+7
    const int b   = blockIdx.y;
    const int tid = threadIdx.x;

    if (tid < SPK) c_sh[tid] = c_trg[b * SPK + tid];
    __syncthreads();
    {
        float acc = style_b[tid];
        const float* wr = style_w + (size_t)tid * SPK;
        #pragma unroll 4
        for (int j = 0; j < SPK; ++j) acc += c_sh[j] * wr[j];
        s_sh[tid] = acc;
    }
    // stage 8-o weight slab (contiguous 40960 B), coalesced float4
    {
        const float* wsrc = weight + (size_t)og * 8 * 1280;
        #pragma unroll
        for (int it = 0; it < 10; ++it)
            *(float4*)&w_l[(it * 256 + tid) * 4] = *(const float4*)&wsrc[(it * 256 + tid) * 4];
    }
    __syncthreads();

    // demod: 32 threads per o
    {
        const int oi   = tid >> 5;
        const int part = tid & 31;
        float a = 0.f;
        #pragma unroll 8
        for (int m = 0; m < 40; ++m) {
            int j = part + m * 32;
            float v = w_l[oi * 1280 + j] * s_sh[j / 5];
            a += v * v;
        }
        a += __shfl_xor(a, 16);
        a += __shfl_xor(a, 8);
        a += __shfl_xor(a, 4);
        a += __shfl_xor(a, 2);
        a += __shfl_xor(a, 1);
        if (part == 0) dm_sh[oi] = rsqrtf(a + 1e-8f);
    }
    __syncthreads();

    // write wmod rows: 320 rows of 32 i (64 B each), PRE-SWIZZLED columns:
    // physical 16B-block = g ^ ((o_l>>1)&3)  <=> byte[5:4] ^= byte[8:7].
    for (int r = tid; r < 320; r += 256) {
        const int oi  = r / 40;
        const int rem = r - oi * 40;
        const int ch  = rem / 5;
        const int k   = rem - ch * 5;
        const int o   = og * 8 + oi;
        const int ot  = o >> 7;
        const int o_l = o & 127;
        const int swz = (o_l >> 1) & 3;
        const float dmv = dm_sh[oi];
        ushort_t* dst = wmod + ((((size_t)(b * 2 + ot) * NCH + ch) * KW + k) * OM + o_l) * 32;
        #pragma unroll
        for (int g = 0; g < 4; ++g) {
            union { ushort_t us[8]; uint4 v; } pk;
            #pragma unroll
            for (int ii = 0; ii < 8; ++ii) {
                int i_l = g * 8 + ii;
                int i_g = ch * 32 + i_l;
                pk.us[ii] = f2bf(w_l[oi * 1280 + i_g * 5 + k] * s_sh[i_g] * dmv);
            }
            *(uint4*)&dst[(g ^ swz) * 8] = pk.v;
        }
    }
}

// ---------------------------------------------------------------------------
// fast conv: 512 thr, 128o x 256t per block, w double-buffered + pipelined.
// All staging register arrays statically indexed (macro-expanded chunks).
__global__ __launch_bounds__(512, 2) void conv_mfma_ws3_kernel(
    const float* __restrict__ x, const ushort_t* __restrict__ wmod,
    float* __restrict__ out)
{
    __shared__ __align__(16) ushort_t w_sh[2][WSLAB];    // 2 x 40960 B
    __shared__ __align__(16) ushort_t x_sh[XROWS * 32];  // 16896 B

    const int b   = blockIdx.z;
    const int ot  = blockIdx.y;
    const int o0  = ot * OM;
    const int t0  = blockIdx.x * TN;
    const int tid = threadIdx.x;

    const int lane  = tid & 63;
    const int wv    = tid >> 6;      // 0..7
    const int wm    = wv >> 2;       // 0..1  (o half)
    const int wn    = wv & 3;        // 0..3  (t quarter)
    const int col16 = lane & 15;
    const int quad  = lane >> 4;

    const int rl = lane;             // x-stage: row within 64-row round
    const int i4 = wv;               // x-stage: channel-quad = wave id (coalesced)

    f32x4 acc[4][4];
    #pragma unroll
    for (int mt = 0; mt < 4; ++mt)
        #pragma unroll
        for (int nt = 0; nt < 4; ++nt)
            acc[mt][nt] = (f32x4){0.f, 0.f, 0.f, 0.f};

    const float* xb = x + (size_t)b * CIN * TT;
    const ushort_t* wslab = wmod + (size_t)(b * 2 + ot) * NCH * WSLAB;

    float xr0[20], xr1[20];          // ping-pong x staging, STATIC indexing only

#define STAGE_W(CH, BUF) do {                                                  \
        const ushort_t* ws_ = wslab + (size_t)(CH) * WSLAB;                    \
        _Pragma("unroll")                                                      \
        for (int s_ = 0; s_ < 5; ++s_) {                                       \
            const int off_ = s_ * 4096 + wv * 512;   /* ushort units */        \
            __builtin_amdgcn_global_load_lds(                                  \
                (const __attribute__((address_space(1))) uint_t*)(ws_ + off_ + lane * 8), \
                (__attribute__((address_space(3))) uint_t*)(&w_sh[BUF][off_]), \
                16, 0, 0);                                                     \
        }                                                                      \
    } while (0)

#define LOAD_X(CH, XR) do {                                                    \
        const float* xp_ = xb + (size_t)((CH) * BI + i4 * 4) * TT;             \
        _Pragma("unroll")                                                      \
        for (int rd_ = 0; rd_ < 5; ++rd_) {                                    \
            int r_ = rd_ * 64 + rl;                                            \
            if (r_ < 260) {                                                    \
                int tg_ = t0 + r_ - 2;                                         \
                tg_ = (tg_ < 0) ? -tg_ : tg_;                                  \
                tg_ = (tg_ > TT - 1) ? (2 * (TT - 1) - tg_) : tg_;             \
                XR[rd_ * 4 + 0] = xp_[tg_];                                    \
                XR[rd_ * 4 + 1] = xp_[TT + tg_];                               \
                XR[rd_ * 4 + 2] = xp_[2 * TT + tg_];                           \
                XR[rd_ * 4 + 3] = xp_[3 * TT + tg_];                           \
            }                                                                  \
        }                                                                      \
    } while (0)

#define PUT_X(XR) do {                                                         \
        _Pragma("unroll")                                                      \
        for (int rd_ = 0; rd_ < 5; ++rd_) {                                    \
            int r_ = rd_ * 64 + rl;                                            \
            if (r_ < 260) {                                                    \
                union { ushort_t us[4]; uint2 u2; } p_;                        \
                p_.us[0] = f2bf(XR[rd_ * 4 + 0]);                              \
                p_.us[1] = f2bf(XR[rd_ * 4 + 1]);                              \
                p_.us[2] = f2bf(XR[rd_ * 4 + 2]);                              \
                p_.us[3] = f2bf(XR[rd_ * 4 + 3]);                              \
                int grp_ = (i4 >> 1) ^ ((r_ ^ (r_ >> 2)) & 3);                 \
                *(uint2*)&x_sh[r_ * 32 + grp_ * 8 + (i4 & 1) * 4] = p_.u2;     \
            }                                                                  \
        }                                                                      \
    } while (0)

#define MFMA_CHUNK(BUF) do {                                                   \
        _Pragma("unroll")                                                      \
        for (int kt_ = 0; kt_ < KW; ++kt_) {                                   \
            short8 a_[4], bf_[4];                                              \
            _Pragma("unroll")                                                  \
            for (int mt_ = 0; mt_ < 4; ++mt_) {                                \
                const int row_  = kt_ * OM + wm * 64 + mt_ * 16 + col16;       \
                const int slot_ = quad ^ ((row_ >> 1) & 3);                    \
                a_[mt_] = *(const short8*)&w_sh[BUF][row_ * 32 + slot_ * 8];   \
            }                                                                  \
            _Pragma("unroll")                                                  \
            for (int nt_ = 0; nt_ < 4; ++nt_) {                                \
                const int r_   = wn * 64 + nt_ * 16 + col16 + kt_;             \
                const int grp_ = quad ^ ((r_ ^ (r_ >> 2)) & 3);                \
                bf_[nt_] = *(const short8*)&x_sh[r_ * 32 + grp_ * 8];          \
            }                                                                  \
            _Pragma("unroll")                                                  \
            for (int mt_ = 0; mt_ < 4; ++mt_)                                  \
                _Pragma("unroll")                                              \
                for (int nt_ = 0; nt_ < 4; ++nt_)                              \
                    acc[mt_][nt_] = __builtin_amdgcn_mfma_f32_16x16x32_bf16(   \
                        a_[mt_], bf_[nt_], acc[mt_][nt_], 0, 0, 0);            \
        }                                                                      \
    } while (0)

// One pipelined chunk. Entering: xr_cur holds x(CH) (loads drained via reg
// scoreboard), w_sh[CUR] gload_lds'ed (drained at the barrier below).
#define CHUNK_BODY(CH, CUR, NXT, XR_CUR, XR_NXT) do {                          \
        PUT_X(XR_CUR);                                                         \
        __syncthreads();  /* A: x_sh+w_sh(CUR) ready; vmcnt drained */         \
        if ((CH) < NCH - 1) {                                                  \
            STAGE_W((CH) + 1, NXT);                                            \
            LOAD_X((CH) + 1, XR_NXT);                                          \
        }                                                                      \
        __builtin_amdgcn_sched_barrier(0); /* pin load issue above MFMA */     \
        MFMA_CHUNK(CUR);                                                       \
        if ((CH) < NCH - 1)                                                    \
            __syncthreads();  /* B: drains (CH)+1 loads, issued one MFMA */    \
                              /* window ago -> cheap */                        \
    } while (0)

    // prologue
    STAGE_W(0, 0);
    LOAD_X(0, xr0);

    CHUNK_BODY(0, 0, 1, xr0, xr1);
    CHUNK_BODY(1, 1, 0, xr1, xr0);
    CHUNK_BODY(2, 0, 1, xr0, xr1);
    CHUNK_BODY(3, 1, 0, xr1, xr0);
    CHUNK_BODY(4, 0, 1, xr0, xr1);
    CHUNK_BODY(5, 1, 0, xr1, xr0);
    CHUNK_BODY(6, 0, 1, xr0, xr1);
    CHUNK_BODY(7, 1, 0, xr1, xr0);

#undef STAGE_W
#undef LOAD_X
#undef PUT_X
#undef MFMA_CHUNK
#undef CHUNK_BODY

    // epilogue: leaky relu + store (demod pre-folded)
    #pragma unroll
    for (int mt = 0; mt < 4; ++mt) {
        #pragma unroll
        for (int nt = 0; nt < 4; ++nt) {
            const int t_o = t0 + wn * 64 + nt * 16 + col16;
            #pragma unroll
            for (int reg = 0; reg < 4; ++reg) {
                const int o_l = wm * 64 + mt * 16 + quad * 4 + reg;
                float v = acc[mt][nt][reg];
                v = (v > 0.f) ? v : 0.2f * v;
                out[((size_t)(b * COUT + o0 + o_l)) * TT + t_o] = v;
            }
        }
    }
}

// ---------------------------------------------------------------------------
// Fallback: R3 kernel verbatim (no workspace), known-good at ~419 us.
__global__ __launch_bounds__(256, 3) void conv_mfma_fb_kernel(
    const float* __restrict__ x, const float* __restrict__ c_trg,
    const float* __restrict__ style_w, const float* __restrict__ style_b,
    const float* __restrict__ weight, float* __restrict__ out)
{
    __shared__ ushort_t x_sh[136 * 32];
    __shared__ ushort_t w_sh[KW * 128 * 32];
    __shared__ float    c_sh[SPK];
    __shared__ float    s_sh[CIN];
    __shared__ float    dm_acc[128];
    __shared__ float    dmv[128];

    const int b   = blockIdx.z;
    const int o0  = blockIdx.y * 128;
    const int t0  = blockIdx.x * 128;
    const int tid = threadIdx.x;

    const int lane  = tid & 63;
    const int wvv   = tid >> 6;
    const int wm    = wvv >> 1;
    const int wn    = wvv & 1;
    const int col16 = lane & 15;
    const int quad  = lane >> 4;

    if (tid < SPK) c_sh[tid] = c_trg[b * SPK + tid];
    if (tid < 128) dm_acc[tid] = 0.f;
    __syncthreads();
    {
        float acc = style_b[tid];
        const float* wr = style_w + (size_t)tid * SPK;
        #pragma unroll 4
        for (int j = 0; j < SPK; ++j) acc += c_sh[j] * wr[j];
        s_sh[tid] = acc;
    }

    f32x4 acc[4][4];
    #pragma unroll
    for (int mt = 0; mt < 4; ++mt)
        #pragma unroll
        for (int nt = 0; nt < 4; ++nt)
            acc[mt][nt] = (f32x4){0.f, 0.f, 0.f, 0.f};

    const float* xb = x + (size_t)b * CIN * TT;

    for (int ch = 0; ch < NCH; ++ch) {
        const int i0 = ch * BI;
        __syncthreads();
        {
            const int i4s = tid >> 5;
            const int rls = tid & 31;
            const float* xp = xb + (size_t)(i0 + i4s * 4) * TT;
            #pragma unroll
            for (int rr = 0; rr < 136; rr += 32) {
                int r = rr + rls;
                if (r < 136) {
                    int tg = t0 + r - 2;
                    tg = (tg < 0) ? -tg : tg;
                    tg = (tg > TT - 1) ? (2 * (TT - 1) - tg) : tg;
                    float v0 = xp[tg];
                    float v1 = xp[TT + tg];
                    float v2 = xp[2 * TT + tg];
                    float v3 = xp[3 * TT + tg];
                    union { ushort_t us[4]; uint2 u2; } p;
                    p.us[0] = f2bf(v0); p.us[1] = f2bf(v1);
                    p.us[2] = f2bf(v2); p.us[3] = f2bf(v3);
                    int grp = (i4s >> 1) ^ (r & 3);
                    *(uint2*)&x_sh[r * 32 + grp * 8 + (i4s & 1) * 4] = p.u2;
                }
            }
        }
        {
            const int i4s = tid & 7;
            #pragma unroll
            for (int pass = 0; pass < 4; ++pass) {
                const int o_l = (tid >> 3) + pass * 32;
                const float* wp = weight + ((size_t)(o0 + o_l) * CIN + i0 + i4s * 4) * KW;
                float q[20];
                #pragma unroll
                for (int f = 0; f < 5; ++f)
                    *(float4*)&q[f * 4] = *(const float4*)(wp + f * 4);
                float sv0 = s_sh[i0 + i4s * 4 + 0];
                float sv1 = s_sh[i0 + i4s * 4 + 1];
                float sv2 = s_sh[i0 + i4s * 4 + 2];
                float sv3 = s_sh[i0 + i4s * 4 + 3];
                float m0[5], m1[5], m2[5], m3[5];
                float psum = 0.f;
                #pragma unroll
                for (int k = 0; k < 5; ++k) {
                    m0[k] = q[0 * 5 + k] * sv0;  psum += m0[k] * m0[k];
                    m1[k] = q[1 * 5 + k] * sv1;  psum += m1[k] * m1[k];
                    m2[k] = q[2 * 5 + k] * sv2;  psum += m2[k] * m2[k];
                    m3[k] = q[3 * 5 + k] * sv3;  psum += m3[k] * m3[k];
                }
                atomicAdd(&dm_acc[o_l], psum);
                #pragma unroll
                for (int k = 0; k < 5; ++k) {
                    union { ushort_t us[4]; uint2 u2; } p;
                    p.us[0] = f2bf(m0[k]); p.us[1] = f2bf(m1[k]);
                    p.us[2] = f2bf(m2[k]); p.us[3] = f2bf(m3[k]);
                    *(uint2*)&w_sh[(k * 128 + o_l) * 32 + i4s * 4] = p.u2;
                }
            }
        }
        __syncthreads();
        #pragma unroll
        for (int kt = 0; kt < KW; ++kt) {
            short8 a[4], bf[4];
            #pragma unroll
            for (int mt = 0; mt < 4; ++mt)
                a[mt] = *(const short8*)&w_sh[(kt * 128 + wm * 64 + mt * 16 + col16) * 32 + quad * 8];
            #pragma unroll
            for (int nt = 0; nt < 4; ++nt) {
                int r   = wn * 64 + nt * 16 + col16 + kt;
                int grp = quad ^ (r & 3);
                bf[nt] = *(const short8*)&x_sh[r * 32 + grp * 8];
            }
            #pragma unroll
            for (int mt = 0; mt < 4; ++mt)
                #pragma unroll
                for (int nt = 0; nt < 4; ++nt)
                    acc[mt][nt] = __builtin_amdgcn_mfma_f32_16x16x32_bf16(
                        a[mt], bf[nt], acc[mt][nt], 0, 0, 0);
        }
    }

    __syncthreads();
    if (tid < 128) dmv[tid] = rsqrtf(dm_acc[tid] + 1e-8f);
    __syncthreads();

    #pragma unroll
    for (int mt = 0; mt < 4; ++mt) {
        #pragma unroll
        for (int nt = 0; nt < 4; ++nt) {
            const int t_o = t0 + wn * 64 + nt * 16 + col16;
            #pragma unroll
            for (int reg = 0; reg < 4; ++reg) {
                const int o_l = wm * 64 + mt * 16 + quad * 4 + reg;
                float v = acc[mt][nt][reg] * dmv[o_l];
                v = (v > 0.f) ? v : 0.2f * v;
                out[((size_t)(b * COUT + o0 + o_l)) * TT + t_o] = v;
            }
        }
    }
}

// ---------------------------------------------------------------------------
extern "C" void kernel_launch(void* const* d_in, const int* in_sizes, int n_in,
                              void* d_out, int out_size, void* d_ws, size_t ws_size,
                              hipStream_t stream)
{
    const float* x       = (const float*)d_in[0];
    const float* c_trg   = (const float*)d_in[1];
    const float* style_w = (const float*)d_in[2];
    const float* style_b = (const float*)d_in[3];
    const float* weight  = (const float*)d_in[4];
    float* out = (float*)d_out;

    if (ws_size >= WMOD_BYTES) {
        // fast path: precompute modulated (pre-swizzled) bf16 weights into d_ws
        ushort_t* wmod = (ushort_t*)d_ws;
        prep_kernel<<<dim3(32, 16), dim3(256), 0, stream>>>(
            c_trg, style_w, style_b, weight, wmod);
        conv_mfma_ws3_kernel<<<dim3(TT / TN, COUT / OM, B_), dim3(512), 0, stream>>>(
            x, wmod, out);
    } else {
        conv_mfma_fb_kernel<<<dim3(TT / 128, COUT / 128, B_), dim3(256), 0, stream>>>(
            x, c_trg, style_w, style_b, weight, out);
    }

    hipMemcpyAsync(out + (size_t)B_ * COUT * TT, c_trg,
                   (size_t)B_ * SPK * sizeof(float),
                   hipMemcpyDeviceToDevice, stream);
}